// Round 18
// baseline (229.819 us; speedup 1.0000x reference)
//
#include <hip/hip_runtime.h>

// Monarch block-MLP, round 18.
//   P1  (0_0): wave-owns-stile form (R17, proven): one barrier/rt, 33KB LDS.
//   P2' (0_1 + 1_0): unchanged (z stays on-chip).
//   P4  (1_1): de-LDS'd — B-frags hoisted directly global->regs (L2-hot,
//        slice XCD-pinned), LDS=0, NO barriers -> compiler pipelines A-loads
//        across rt iterations; 8 s' per wave (no duplicate A-reads).
// y0t lives in d_out (dead before P4 writes out); y2t2 lives in ws.

typedef __attribute__((ext_vector_type(8))) short short8;
typedef __attribute__((ext_vector_type(4))) float floatx4;
typedef unsigned int uint;
typedef unsigned short ushort;

#define MFMA32(a, b, c) __builtin_amdgcn_mfma_f32_16x16x32_bf16(a, b, c, 0, 0, 0)

__device__ __forceinline__ ushort f2bf(float f) {
    uint u = __float_as_uint(f);
    uint r = 0x7FFFu + ((u >> 16) & 1u);
    return (ushort)((u + r) >> 16);
}
__device__ __forceinline__ short8 ld8(const ushort* p) {
    return *reinterpret_cast<const short8*>(p);
}
// LDS-ordering barrier that does NOT drain vmcnt.
__device__ __forceinline__ void lgkm_barrier() {
    __builtin_amdgcn_sched_barrier(0);
    asm volatile("s_waitcnt lgkmcnt(0)" ::: "memory");
    __builtin_amdgcn_s_barrier();
    __builtin_amdgcn_sched_barrier(0);
}

// One launch, 4 weight transposes, all plain: out[b][c][r] = bf16(in[b][r][c]).
__global__ void prep_weights(const float* __restrict__ w0, const float* __restrict__ w1,
                             const float* __restrict__ w2, const float* __restrict__ w3,
                             ushort* __restrict__ w0t, ushort* __restrict__ w1t,
                             ushort* __restrict__ w2t, ushort* __restrict__ w3t) {
    int stride = gridDim.x * blockDim.x;
    for (int idx = blockIdx.x * blockDim.x + threadIdx.x; idx < 4 * 524288; idx += stride) {
        const int seg = idx >> 19;
        const int local = idx & 524287;
        const float* in; ushort* out; int R, C;
        if (seg == 0)      { in = w0; out = w0t; R = 64;  C = 128; }
        else if (seg == 1) { in = w1; out = w1t; R = 64;  C = 64;  }
        else if (seg == 2) { in = w2; out = w2t; R = 64;  C = 64;  }
        else               { in = w3; out = w3t; R = 128; C = 64;  }
        const int rc = R * C;
        const int b = local / rc;
        const int rem = local - b * rc;
        const int c = rem / R;
        const int r = rem - c * R;
        out[local] = f2bf(in[(size_t)(b * R + r) * C + c]);
    }
}

// MFMA 16x16x32 bf16 layouts (m89-verified):
//   A: row=lane&15, k=(lane>>4)*8+i ; B: col=lane&15, same k
//   D: col=lane&15, row=(lane>>4)*4+reg

// ---- P1: stage 0_0. x (f32) -> y0t[b][sl8][s128][kb8] ----
// wave w = stile w (16 s), all 8 kb of the slice.
__global__ __launch_bounds__(512, 4) void pass1_k(
    const float* __restrict__ x,       // [bs][4096]
    const ushort* __restrict__ w0t,    // [64 kb][128 s][64 m] plain
    ushort* __restrict__ y0t)          // [bs][8][128][8]  (= d_out alias)
{
    const int tid = threadIdx.x, lane = tid & 63, wv = tid >> 6;
    const int l15 = lane & 15, l4 = lane >> 4;
    const int slice = blockIdx.x & 7;          // 8 kb per slice, XCD-pinned
    const int r0 = (blockIdx.x >> 3) * 128;

    // x staging: [buf2][row16][528] bf16 (row pad 512->528 -> 8-bank row skew)
    __shared__ __align__(16) ushort xs[2][16][528];   // 33792 B total LDS

    // one-time B-frag hoist from global (L2-hot): all 8 kb x stile wv
    short8 wb[8][2];
#pragma unroll
    for (int kb = 0; kb < 8; ++kb)
#pragma unroll
        for (int kh = 0; kh < 2; ++kh)
            wb[kb][kh] = ld8(w0t + ((size_t)(slice * 8 + kb) * 128 + wv * 16 + l15) * 64
                                 + kh * 32 + l4 * 8);

    const int lrow = lane >> 2;        // 0..15 (load-phase row)
    const int cq   = lane & 3;         // col quarter (16 floats)

    for (int rt = 0; rt < 8; ++rt) {
        // ---- phase L: wave wv loads+casts kb=wv (16 rows x 64 f32, unique) ----
        {
            const float* xp = x + (size_t)(r0 + rt * 16 + lrow) * 4096
                                + (slice * 8 + wv) * 64 + cq * 16;
            floatx4 u0 = *reinterpret_cast<const floatx4*>(xp);
            floatx4 u1 = *reinterpret_cast<const floatx4*>(xp + 4);
            floatx4 u2 = *reinterpret_cast<const floatx4*>(xp + 8);
            floatx4 u3 = *reinterpret_cast<const floatx4*>(xp + 12);
            short8 v0, v1;
#pragma unroll
            for (int i = 0; i < 4; ++i) {
                v0[i]     = (short)f2bf(u0[i]);
                v0[i + 4] = (short)f2bf(u1[i]);
                v1[i]     = (short)f2bf(u2[i]);
                v1[i + 4] = (short)f2bf(u3[i]);
            }
            ushort* dst = &xs[rt & 1][lrow][wv * 64 + cq * 16];
            *reinterpret_cast<short8*>(dst)     = v0;
            *reinterpret_cast<short8*>(dst + 8) = v1;
        }
        lgkm_barrier();                // xs[rt&1] complete; vmcnt untouched

        // ---- phase C: stile wv, all 8 kb; direct b128 stores ----
        floatx4 d[8];
#pragma unroll
        for (int kb = 0; kb < 8; ++kb) {
            short8 a0 = ld8(&xs[rt & 1][l15][kb * 64 + l4 * 8]);
            short8 a1 = ld8(&xs[rt & 1][l15][kb * 64 + 32 + l4 * 8]);
            floatx4 t = (floatx4){0.f, 0.f, 0.f, 0.f};
            t = MFMA32(a0, wb[kb][0], t);
            t = MFMA32(a1, wb[kb][1], t);
            d[kb] = t;
        }
#pragma unroll
        for (int rg = 0; rg < 4; ++rg) {
            short8 pk;
#pragma unroll
            for (int kb = 0; kb < 8; ++kb) pk[kb] = (short)f2bf(d[kb][rg]);
            *reinterpret_cast<short8*>(
                y0t + (size_t)(r0 + rt * 16 + l4 * 4 + rg) * 8192
                    + slice * 1024 + (wv * 16 + l15) * 8) = pk;
        }
    }
}

// ---- P2': fused stage 0_1 + 1_0. y0t -> y2t2, z stays on-chip ----
__global__ __launch_bounds__(512, 4) void pass23_k(
    const ushort* __restrict__ y0t,    // [bs][8][128][8]
    const ushort* __restrict__ w1t,    // [128 s][64 j][64 kb]
    const ushort* __restrict__ w2t,    // [128 n][64 j2][64 m]
    const float* __restrict__ b1,      // [8192]
    ushort* __restrict__ y2t)          // [bs][16 chunk][64 c][8 nl]
{
    const int tid = threadIdx.x, lane = tid & 63, wv = tid >> 6;
    const int l15 = lane & 15, l4 = lane >> 4;
    const int sblk = blockIdx.x & 15;          // 8 n-blocks per wg
    const int r0 = (blockIdx.x >> 4) * 128;
    const int s = sblk * 8 + wv;               // wave's n-block 0..127

    __shared__ __align__(16) ushort zst[8 * 1024];   // wave-local z: 2KB/wave
    __shared__ __align__(16) ushort sbuf[16 * 512];  // [r16][c64][nl8] 16KB
    char* zb = (char*)zst + wv * 2048;

    // one-time weight frag hoist (global -> regs, 64 VGPR)
    short8 wbf[4][2], wc[4][2];
    float bvv[4];
#pragma unroll
    for (int jq = 0; jq < 4; ++jq) {
#pragma unroll
        for (int kh = 0; kh < 2; ++kh) {
            wbf[jq][kh] = ld8(w1t + ((size_t)s * 64 + jq * 16 + l15) * 64
                                  + kh * 32 + l4 * 8);
            wc[jq][kh]  = ld8(w2t + ((size_t)s * 64 + jq * 16 + l15) * 64
                                  + kh * 32 + l4 * 8);
        }
        bvv[jq] = b1[s * 64 + jq * 16 + l15];
    }

    const ushort* abase = y0t + (size_t)(r0 + l15) * 8192 + l4 * 1024 + s * 8;
    short8 a0 = ld8(abase), a1 = ld8(abase + 4096);

    for (int rt = 0; rt < 8; ++rt) {
        // ---- stage 0_1: z-frag = elu(y0 @ w1 + b1) -> wave-local zst ----
#pragma unroll
        for (int jq = 0; jq < 4; ++jq) {
            floatx4 t = (floatx4){0.f, 0.f, 0.f, 0.f};
            t = MFMA32(a0, wbf[jq][0], t);
            t = MFMA32(a1, wbf[jq][1], t);
#pragma unroll
            for (int rg = 0; rg < 4; ++rg) {
                float v = t[rg] + bvv[jq];
                v = v > 0.f ? v : (__expf(v) - 1.f);
                const int r = l4 * 4 + rg;
                *reinterpret_cast<ushort*>(
                    zb + ((r * 128 + (jq * 16 + l15) * 2) ^ ((r & 7) << 4))) = f2bf(v);
            }
        }
        // wave-local LDS ordering (no cross-wave barrier needed for zst)
        __builtin_amdgcn_sched_barrier(0);
        asm volatile("s_waitcnt lgkmcnt(0)" ::: "memory");
        __builtin_amdgcn_sched_barrier(0);

        // ---- stage 1_0: y2 = z @ w2 ----
        short8 za0 = *reinterpret_cast<const short8*>(
            zb + ((l15 * 128 + l4 * 16) ^ ((l15 & 7) << 4)));
        short8 za1 = *reinterpret_cast<const short8*>(
            zb + ((l15 * 128 + 64 + l4 * 16) ^ ((l15 & 7) << 4)));
        floatx4 acc[4];
#pragma unroll
        for (int jq = 0; jq < 4; ++jq) {
            floatx4 t = (floatx4){0.f, 0.f, 0.f, 0.f};
            t = MFMA32(za0, wc[jq][0], t);
            t = MFMA32(za1, wc[jq][1], t);
            acc[jq] = t;
        }

        // issue next rt's A-loads now; they fly across the sbuf barriers
        if (rt + 1 < 8) {
            const ushort* ap = abase + (size_t)(rt + 1) * 16 * 8192;
            a0 = ld8(ap);
            a1 = ld8(ap + 4096);
        }

        // ---- stage y2 -> sbuf -> coalesced y2t2 stores ----
#pragma unroll
        for (int jq = 0; jq < 4; ++jq)
#pragma unroll
            for (int rg = 0; rg < 4; ++rg) {
                const int r = l4 * 4 + rg;
                *reinterpret_cast<ushort*>(
                    (char*)sbuf + r * 1024 + (jq * 16 + l15) * 16 + wv * 2) =
                    f2bf(acc[jq][rg]);
            }
        lgkm_barrier();
#pragma unroll
        for (int q2 = 0; q2 < 2; ++q2) {
            const int idx = q2 * 512 + tid;
            const int row = idx >> 6, c = idx & 63;
            short8 v = *reinterpret_cast<const short8*>(
                (char*)sbuf + row * 1024 + c * 16);
            *reinterpret_cast<short8*>(
                y2t + (size_t)(r0 + rt * 16 + row) * 8192 + sblk * 512 + c * 8) = v;
        }
        lgkm_barrier();
    }
}

// ---- P4: stage 1_1. y2t2 -> out f32 (+b3); 8 s' per wg, NO LDS ----
__global__ __launch_bounds__(512, 2) void pass4_k(
    const ushort* __restrict__ y2t,    // [bs][16 chunk][64 c][8 nl]
    const ushort* __restrict__ w3t,    // [64 s][64 j][128 k] plain
    const float* __restrict__ b3,      // [4096]
    float* __restrict__ out)           // [bs][4096]
{
    const int tid = threadIdx.x, lane = tid & 63, wv = tid >> 6;
    const int l15 = lane & 15, l4 = lane >> 4;
    const int slice = blockIdx.x & 7;
    const int r0 = (blockIdx.x >> 3) * 128;
    const int s = slice * 8 + wv;              // wave's out-block s'

    // one-time B-frag hoist directly from global (L2-hot, slice XCD-pinned)
    short8 wb[4][4];
#pragma unroll
    for (int jq = 0; jq < 4; ++jq)
#pragma unroll
        for (int kq = 0; kq < 4; ++kq)
            wb[jq][kq] = ld8(w3t + ((size_t)s * 64 + jq * 16 + l15) * 128
                                 + kq * 32 + l4 * 8);
    float bvv[4];
#pragma unroll
    for (int jq = 0; jq < 4; ++jq) bvv[jq] = b3[s * 64 + jq * 16 + l15];

    // no barriers in the loop -> compiler pipelines A-loads across rt
    for (int rt = 0; rt < 8; ++rt) {
        short8 a[4];
#pragma unroll
        for (int kq = 0; kq < 4; ++kq)
            a[kq] = ld8(y2t + (size_t)(r0 + rt * 16 + l15) * 8192
                            + (kq * 4 + l4) * 512 + s * 8);
        floatx4 acc[4];
#pragma unroll
        for (int jq = 0; jq < 4; ++jq) acc[jq] = (floatx4){0.f, 0.f, 0.f, 0.f};
#pragma unroll
        for (int kq = 0; kq < 4; ++kq)
#pragma unroll
            for (int jq = 0; jq < 4; ++jq)
                acc[jq] = MFMA32(a[kq], wb[jq][kq], acc[jq]);
#pragma unroll
        for (int jq = 0; jq < 4; ++jq) {
#pragma unroll
            for (int rg = 0; rg < 4; ++rg)
                out[(size_t)(r0 + rt * 16 + l4 * 4 + rg) * 4096
                    + s * 64 + jq * 16 + l15] = acc[jq][rg] + bvv[jq];
        }
    }
}

extern "C" void kernel_launch(void* const* d_in, const int* in_sizes, int n_in,
                              void* d_out, int out_size, void* d_ws, size_t ws_size,
                              hipStream_t stream) {
    const float* x  = (const float*)d_in[0];
    const float* w0 = (const float*)d_in[1];
    const float* w1 = (const float*)d_in[2];
    const float* b1 = (const float*)d_in[3];
    const float* w2 = (const float*)d_in[4];
    const float* w3 = (const float*)d_in[5];
    const float* b3 = (const float*)d_in[6];
    float* out = (float*)d_out;

    const int bs = in_sizes[0] / 4096;

    // ws (u16): y2t2[bs*8192] | w0t | w1t | w2t | w3t   (y0t lives in d_out)
    ushort* y2t2 = (ushort*)d_ws;
    const size_t zElems = (size_t)bs * 8192;
    ushort* w0t = y2t2 + zElems;
    ushort* w1t = w0t + 64 * 128 * 64;
    ushort* w2t = w1t + 128 * 64 * 64;
    ushort* w3t = w2t + 128 * 64 * 64;
    const size_t need = (zElems + 4ull * 524288) * sizeof(ushort);
    if (n_in < 7 || (bs & 127) || ws_size < need) return;

    ushort* y0t = (ushort*)d_out;      // dead until P4 overwrites it

    prep_weights<<<dim3(1024), dim3(256), 0, stream>>>(
        w0, w1, w2, w3, w0t, w1t, w2t, w3t);

    pass1_k <<<dim3((bs / 128) * 8),  dim3(512), 0, stream>>>(x, w0t, y0t);
    pass23_k<<<dim3((bs / 128) * 16), dim3(512), 0, stream>>>(y0t, w1t, w2t, b1, y2t2);
    pass4_k <<<dim3((bs / 128) * 8),  dim3(512), 0, stream>>>(y2t2, w3t, b3, out);
}

// Round 19
// 217.325 us; speedup vs baseline: 1.0575x; 1.0575x over previous
//
#include <hip/hip_runtime.h>

// Monarch block-MLP, round 19.
//   P1  (0_0): wave-owns-stile (R17, proven): one barrier/rt, 33KB LDS.
//   P2' (0_1 + 1_0): unchanged (z stays on-chip).
//   P4  (1_1): 4 s' per wg x 2 row-halves -> unique A-reads per wave,
//        weights in 64KB LDS (2 wg/CU), barrier-free main loop.
// y0t lives in d_out (dead before P4 writes out); y2t2 lives in ws.

typedef __attribute__((ext_vector_type(8))) short short8;
typedef __attribute__((ext_vector_type(4))) float floatx4;
typedef unsigned int uint;
typedef unsigned short ushort;

#define MFMA32(a, b, c) __builtin_amdgcn_mfma_f32_16x16x32_bf16(a, b, c, 0, 0, 0)

__device__ __forceinline__ ushort f2bf(float f) {
    uint u = __float_as_uint(f);
    uint r = 0x7FFFu + ((u >> 16) & 1u);
    return (ushort)((u + r) >> 16);
}
__device__ __forceinline__ short8 ld8(const ushort* p) {
    return *reinterpret_cast<const short8*>(p);
}
__device__ __forceinline__ void gload_lds16(const void* g, void* l) {
    __builtin_amdgcn_global_load_lds(
        (const __attribute__((address_space(1))) unsigned int*)g,
        (__attribute__((address_space(3))) unsigned int*)l, 16, 0, 0);
}
// LDS-ordering barrier that does NOT drain vmcnt.
__device__ __forceinline__ void lgkm_barrier() {
    __builtin_amdgcn_sched_barrier(0);
    asm volatile("s_waitcnt lgkmcnt(0)" ::: "memory");
    __builtin_amdgcn_s_barrier();
    __builtin_amdgcn_sched_barrier(0);
}

// One launch, 4 weight transposes. w0/w1/w2 plain, w3 swizzled.
// Plain: out[b][c][r] = bf16(in[b][r][c]). Swz: same element at byte
// ((c*R+r)*2)^((c&7)<<4) within its block.
__global__ void prep_weights(const float* __restrict__ w0, const float* __restrict__ w1,
                             const float* __restrict__ w2, const float* __restrict__ w3,
                             ushort* __restrict__ w0t, ushort* __restrict__ w1t,
                             ushort* __restrict__ w2t, ushort* __restrict__ w3s) {
    int stride = gridDim.x * blockDim.x;
    for (int idx = blockIdx.x * blockDim.x + threadIdx.x; idx < 4 * 524288; idx += stride) {
        const int seg = idx >> 19;
        const int local = idx & 524287;
        const float* in; ushort* out; int R, C; bool swz;
        if (seg == 0)      { in = w0; out = w0t; R = 64;  C = 128; swz = false; }
        else if (seg == 1) { in = w1; out = w1t; R = 64;  C = 64;  swz = false; }
        else if (seg == 2) { in = w2; out = w2t; R = 64;  C = 64;  swz = false; }
        else               { in = w3; out = w3s; R = 128; C = 64;  swz = true;  }
        const int rc = R * C;
        const int b = local / rc;
        const int rem = local - b * rc;
        const int c = rem / R;
        const int r = rem - c * R;
        const ushort v = f2bf(in[(size_t)(b * R + r) * C + c]);
        if (swz) {
            int byteoff = ((c * R + r) * 2) ^ ((c & 7) << 4);
            *reinterpret_cast<ushort*>((char*)out + (size_t)b * rc * 2 + byteoff) = v;
        } else {
            out[local] = v;
        }
    }
}

// MFMA 16x16x32 bf16 layouts (m89-verified):
//   A: row=lane&15, k=(lane>>4)*8+i ; B: col=lane&15, same k
//   D: col=lane&15, row=(lane>>4)*4+reg

// ---- P1: stage 0_0. x (f32) -> y0t[b][sl8][s128][kb8] ----
// wave w = stile w (16 s), all 8 kb of the slice.
__global__ __launch_bounds__(512, 4) void pass1_k(
    const float* __restrict__ x,       // [bs][4096]
    const ushort* __restrict__ w0t,    // [64 kb][128 s][64 m] plain
    ushort* __restrict__ y0t)          // [bs][8][128][8]  (= d_out alias)
{
    const int tid = threadIdx.x, lane = tid & 63, wv = tid >> 6;
    const int l15 = lane & 15, l4 = lane >> 4;
    const int slice = blockIdx.x & 7;          // 8 kb per slice, XCD-pinned
    const int r0 = (blockIdx.x >> 3) * 128;

    // x staging: [buf2][row16][528] bf16 (row pad 512->528 -> 8-bank row skew)
    __shared__ __align__(16) ushort xs[2][16][528];   // 33792 B total LDS

    // one-time B-frag hoist from global (L2-hot): all 8 kb x stile wv
    short8 wb[8][2];
#pragma unroll
    for (int kb = 0; kb < 8; ++kb)
#pragma unroll
        for (int kh = 0; kh < 2; ++kh)
            wb[kb][kh] = ld8(w0t + ((size_t)(slice * 8 + kb) * 128 + wv * 16 + l15) * 64
                                 + kh * 32 + l4 * 8);

    const int lrow = lane >> 2;        // 0..15 (load-phase row)
    const int cq   = lane & 3;         // col quarter (16 floats)

    for (int rt = 0; rt < 8; ++rt) {
        // ---- phase L: wave wv loads+casts kb=wv (16 rows x 64 f32, unique) ----
        {
            const float* xp = x + (size_t)(r0 + rt * 16 + lrow) * 4096
                                + (slice * 8 + wv) * 64 + cq * 16;
            floatx4 u0 = *reinterpret_cast<const floatx4*>(xp);
            floatx4 u1 = *reinterpret_cast<const floatx4*>(xp + 4);
            floatx4 u2 = *reinterpret_cast<const floatx4*>(xp + 8);
            floatx4 u3 = *reinterpret_cast<const floatx4*>(xp + 12);
            short8 v0, v1;
#pragma unroll
            for (int i = 0; i < 4; ++i) {
                v0[i]     = (short)f2bf(u0[i]);
                v0[i + 4] = (short)f2bf(u1[i]);
                v1[i]     = (short)f2bf(u2[i]);
                v1[i + 4] = (short)f2bf(u3[i]);
            }
            ushort* dst = &xs[rt & 1][lrow][wv * 64 + cq * 16];
            *reinterpret_cast<short8*>(dst)     = v0;
            *reinterpret_cast<short8*>(dst + 8) = v1;
        }
        lgkm_barrier();                // xs[rt&1] complete; vmcnt untouched

        // ---- phase C: stile wv, all 8 kb; direct b128 stores ----
        floatx4 d[8];
#pragma unroll
        for (int kb = 0; kb < 8; ++kb) {
            short8 a0 = ld8(&xs[rt & 1][l15][kb * 64 + l4 * 8]);
            short8 a1 = ld8(&xs[rt & 1][l15][kb * 64 + 32 + l4 * 8]);
            floatx4 t = (floatx4){0.f, 0.f, 0.f, 0.f};
            t = MFMA32(a0, wb[kb][0], t);
            t = MFMA32(a1, wb[kb][1], t);
            d[kb] = t;
        }
#pragma unroll
        for (int rg = 0; rg < 4; ++rg) {
            short8 pk;
#pragma unroll
            for (int kb = 0; kb < 8; ++kb) pk[kb] = (short)f2bf(d[kb][rg]);
            *reinterpret_cast<short8*>(
                y0t + (size_t)(r0 + rt * 16 + l4 * 4 + rg) * 8192
                    + slice * 1024 + (wv * 16 + l15) * 8) = pk;
        }
    }
}

// ---- P2': fused stage 0_1 + 1_0. y0t -> y2t2, z stays on-chip ----
__global__ __launch_bounds__(512, 4) void pass23_k(
    const ushort* __restrict__ y0t,    // [bs][8][128][8]
    const ushort* __restrict__ w1t,    // [128 s][64 j][64 kb]
    const ushort* __restrict__ w2t,    // [128 n][64 j2][64 m]
    const float* __restrict__ b1,      // [8192]
    ushort* __restrict__ y2t)          // [bs][16 chunk][64 c][8 nl]
{
    const int tid = threadIdx.x, lane = tid & 63, wv = tid >> 6;
    const int l15 = lane & 15, l4 = lane >> 4;
    const int sblk = blockIdx.x & 15;          // 8 n-blocks per wg
    const int r0 = (blockIdx.x >> 4) * 128;
    const int s = sblk * 8 + wv;               // wave's n-block 0..127

    __shared__ __align__(16) ushort zst[8 * 1024];   // wave-local z: 2KB/wave
    __shared__ __align__(16) ushort sbuf[16 * 512];  // [r16][c64][nl8] 16KB
    char* zb = (char*)zst + wv * 2048;

    // one-time weight frag hoist (global -> regs, 64 VGPR)
    short8 wbf[4][2], wc[4][2];
    float bvv[4];
#pragma unroll
    for (int jq = 0; jq < 4; ++jq) {
#pragma unroll
        for (int kh = 0; kh < 2; ++kh) {
            wbf[jq][kh] = ld8(w1t + ((size_t)s * 64 + jq * 16 + l15) * 64
                                  + kh * 32 + l4 * 8);
            wc[jq][kh]  = ld8(w2t + ((size_t)s * 64 + jq * 16 + l15) * 64
                                  + kh * 32 + l4 * 8);
        }
        bvv[jq] = b1[s * 64 + jq * 16 + l15];
    }

    const ushort* abase = y0t + (size_t)(r0 + l15) * 8192 + l4 * 1024 + s * 8;
    short8 a0 = ld8(abase), a1 = ld8(abase + 4096);

    for (int rt = 0; rt < 8; ++rt) {
        // ---- stage 0_1: z-frag = elu(y0 @ w1 + b1) -> wave-local zst ----
#pragma unroll
        for (int jq = 0; jq < 4; ++jq) {
            floatx4 t = (floatx4){0.f, 0.f, 0.f, 0.f};
            t = MFMA32(a0, wbf[jq][0], t);
            t = MFMA32(a1, wbf[jq][1], t);
#pragma unroll
            for (int rg = 0; rg < 4; ++rg) {
                float v = t[rg] + bvv[jq];
                v = v > 0.f ? v : (__expf(v) - 1.f);
                const int r = l4 * 4 + rg;
                *reinterpret_cast<ushort*>(
                    zb + ((r * 128 + (jq * 16 + l15) * 2) ^ ((r & 7) << 4))) = f2bf(v);
            }
        }
        // wave-local LDS ordering (no cross-wave barrier needed for zst)
        __builtin_amdgcn_sched_barrier(0);
        asm volatile("s_waitcnt lgkmcnt(0)" ::: "memory");
        __builtin_amdgcn_sched_barrier(0);

        // ---- stage 1_0: y2 = z @ w2 ----
        short8 za0 = *reinterpret_cast<const short8*>(
            zb + ((l15 * 128 + l4 * 16) ^ ((l15 & 7) << 4)));
        short8 za1 = *reinterpret_cast<const short8*>(
            zb + ((l15 * 128 + 64 + l4 * 16) ^ ((l15 & 7) << 4)));
        floatx4 acc[4];
#pragma unroll
        for (int jq = 0; jq < 4; ++jq) {
            floatx4 t = (floatx4){0.f, 0.f, 0.f, 0.f};
            t = MFMA32(za0, wc[jq][0], t);
            t = MFMA32(za1, wc[jq][1], t);
            acc[jq] = t;
        }

        // issue next rt's A-loads now; they fly across the sbuf barriers
        if (rt + 1 < 8) {
            const ushort* ap = abase + (size_t)(rt + 1) * 16 * 8192;
            a0 = ld8(ap);
            a1 = ld8(ap + 4096);
        }

        // ---- stage y2 -> sbuf -> coalesced y2t2 stores ----
#pragma unroll
        for (int jq = 0; jq < 4; ++jq)
#pragma unroll
            for (int rg = 0; rg < 4; ++rg) {
                const int r = l4 * 4 + rg;
                *reinterpret_cast<ushort*>(
                    (char*)sbuf + r * 1024 + (jq * 16 + l15) * 16 + wv * 2) =
                    f2bf(acc[jq][rg]);
            }
        lgkm_barrier();
#pragma unroll
        for (int q2 = 0; q2 < 2; ++q2) {
            const int idx = q2 * 512 + tid;
            const int row = idx >> 6, c = idx & 63;
            short8 v = *reinterpret_cast<const short8*>(
                (char*)sbuf + row * 1024 + c * 16);
            *reinterpret_cast<short8*>(
                y2t + (size_t)(r0 + rt * 16 + row) * 8192 + sblk * 512 + c * 8) = v;
        }
        lgkm_barrier();
    }
}

// ---- P4: stage 1_1. y2t2 -> out f32 (+b3); 4 s' x 2 row-halves per wg ----
__global__ __launch_bounds__(512, 4) void pass4_k(
    const ushort* __restrict__ y2t,    // [bs][16 chunk][64 c][8 nl]
    const ushort* __restrict__ w3s,    // [64 s][64 j][128 k] swz per block
    const float* __restrict__ b3,      // [4096]
    float* __restrict__ out)           // [bs][4096]
{
    const int tid = threadIdx.x, lane = tid & 63, wv = tid >> 6;
    const int l15 = lane & 15, l4 = lane >> 4;
    const int slice = blockIdx.x & 15;         // 4 s' per slice (2/XCD, L2-hot)
    const int r0 = (blockIdx.x >> 4) * 128;
    const int sq = wv & 3;                     // s' within slice
    const int rh = wv >> 2;                    // row half (rt 0-3 / 4-7)
    const int s = slice * 4 + sq;              // wave's out-block s'

    __shared__ __align__(16) ushort wlds[4 * 8192];    // 64 KB -> 2 wg/CU
    {
        const ushort* src = w3s + (size_t)slice * 4 * 8192;
        for (int i = 0; i < 8; ++i)
            gload_lds16(src + i * 4096 + tid * 8, &wlds[i * 4096 + tid * 8]);
    }
    __syncthreads();

    short8 wb[4][4];
    const char* wp = (const char*)wlds + sq * 16384;
#pragma unroll
    for (int jq = 0; jq < 4; ++jq)
#pragma unroll
        for (int kq = 0; kq < 4; ++kq) {
            const int byteoff =
                (((jq * 16 + l15) * 128 + kq * 32 + l4 * 8) * 2) ^ ((l15 & 7) << 4);
            wb[jq][kq] = *reinterpret_cast<const short8*>(wp + byteoff);
        }
    float bvv[4];
#pragma unroll
    for (int jq = 0; jq < 4; ++jq) bvv[jq] = b3[s * 64 + jq * 16 + l15];

    // barrier-free loop; each wave owns (s', 4 rt) -> unique A-reads
    for (int rr = 0; rr < 4; ++rr) {
        const int rt = rh * 4 + rr;
        short8 a[4];
#pragma unroll
        for (int kq = 0; kq < 4; ++kq)
            a[kq] = ld8(y2t + (size_t)(r0 + rt * 16 + l15) * 8192
                            + (kq * 4 + l4) * 512 + s * 8);
        floatx4 acc[4];
#pragma unroll
        for (int jq = 0; jq < 4; ++jq) acc[jq] = (floatx4){0.f, 0.f, 0.f, 0.f};
#pragma unroll
        for (int kq = 0; kq < 4; ++kq)
#pragma unroll
            for (int jq = 0; jq < 4; ++jq)
                acc[jq] = MFMA32(a[kq], wb[jq][kq], acc[jq]);
#pragma unroll
        for (int jq = 0; jq < 4; ++jq) {
#pragma unroll
            for (int rg = 0; rg < 4; ++rg)
                out[(size_t)(r0 + rt * 16 + l4 * 4 + rg) * 4096
                    + s * 64 + jq * 16 + l15] = acc[jq][rg] + bvv[jq];
        }
    }
}

extern "C" void kernel_launch(void* const* d_in, const int* in_sizes, int n_in,
                              void* d_out, int out_size, void* d_ws, size_t ws_size,
                              hipStream_t stream) {
    const float* x  = (const float*)d_in[0];
    const float* w0 = (const float*)d_in[1];
    const float* w1 = (const float*)d_in[2];
    const float* b1 = (const float*)d_in[3];
    const float* w2 = (const float*)d_in[4];
    const float* w3 = (const float*)d_in[5];
    const float* b3 = (const float*)d_in[6];
    float* out = (float*)d_out;

    const int bs = in_sizes[0] / 4096;

    // ws (u16): y2t2[bs*8192] | w0t | w1t | w2t | w3s   (y0t lives in d_out)
    ushort* y2t2 = (ushort*)d_ws;
    const size_t zElems = (size_t)bs * 8192;
    ushort* w0t = y2t2 + zElems;
    ushort* w1t = w0t + 64 * 128 * 64;
    ushort* w2t = w1t + 128 * 64 * 64;
    ushort* w3s = w2t + 128 * 64 * 64;
    const size_t need = (zElems + 4ull * 524288) * sizeof(ushort);
    if (n_in < 7 || (bs & 127) || ws_size < need) return;

    ushort* y0t = (ushort*)d_out;      // dead until P4 overwrites it

    prep_weights<<<dim3(1024), dim3(256), 0, stream>>>(
        w0, w1, w2, w3, w0t, w1t, w2t, w3s);

    pass1_k <<<dim3((bs / 128) * 8),  dim3(512), 0, stream>>>(x, w0t, y0t);
    pass23_k<<<dim3((bs / 128) * 16), dim3(512), 0, stream>>>(y0t, w1t, w2t, b1, y2t2);
    pass4_k <<<dim3((bs / 128) * 16), dim3(512), 0, stream>>>(y2t2, w3s, b3, out);
}